// Round 1
// baseline (175.194 us; speedup 1.0000x reference)
//
#include <hip/hip_runtime.h>
#include <math.h>

#define MARGIN 0.4f
#define EPSF   1e-3f
#define SCALE  64.0f

// Bulk: out = logits * 64 for every element (vectorized float4, grid-stride).
__global__ void adaface_scale_kernel(const float4* __restrict__ in,
                                     float4* __restrict__ out,
                                     long n4, const float* __restrict__ in_s,
                                     float* __restrict__ out_s, long n_tail_start, long n) {
    long i = (long)blockIdx.x * blockDim.x + threadIdx.x;
    long stride = (long)gridDim.x * blockDim.x;
    for (long k = i; k < n4; k += stride) {
        float4 v = in[k];
        v.x *= SCALE; v.y *= SCALE; v.z *= SCALE; v.w *= SCALE;
        out[k] = v;
    }
    // scalar tail (empty when n % 4 == 0, as here: 1024*100000)
    for (long k = n_tail_start + i; k < n; k += stride) {
        out_s[k] = in_s[k] * SCALE;
    }
}

// Fixup: one block. Compute mean/std of clipped norms over positive rows,
// then rewrite the single target element of each positive row.
__global__ __launch_bounds__(1024)
void adaface_fixup_kernel(const float* __restrict__ logits,
                          const float* __restrict__ norms,
                          const int* __restrict__ labels,
                          float* __restrict__ out, int B, int C) {
    __shared__ float red_a[16];
    __shared__ float red_b[16];
    __shared__ float s_cnt, s_mean, s_std;

    int tid  = threadIdx.x;
    int lane = tid & 63;
    int wave = tid >> 6;
    int nw   = (blockDim.x + 63) >> 6;

    float sn  = 0.0f;
    int   lab = -1;
    bool  pos = false;
    if (tid < B) {
        sn  = fminf(fmaxf(norms[tid], 1e-3f), 100.0f);
        lab = labels[tid];
        pos = (lab != -1);
    }
    float posf = pos ? 1.0f : 0.0f;

    // Reduction 1: count of positives and sum of sn over positives.
    float a = posf;
    float b = pos ? sn : 0.0f;
    for (int off = 32; off >= 1; off >>= 1) {
        a += __shfl_down(a, off);
        b += __shfl_down(b, off);
    }
    if (lane == 0) { red_a[wave] = a; red_b[wave] = b; }
    __syncthreads();
    if (wave == 0) {
        float aa = (lane < nw) ? red_a[lane] : 0.0f;
        float bb = (lane < nw) ? red_b[lane] : 0.0f;
        for (int off = 32; off >= 1; off >>= 1) {
            aa += __shfl_down(aa, off);
            bb += __shfl_down(bb, off);
        }
        if (lane == 0) { s_cnt = aa; s_mean = bb / aa; }
    }
    __syncthreads();

    // Reduction 2: unbiased variance over positives.
    float mean = s_mean;
    float d = sn - mean;
    float v = pos ? d * d : 0.0f;
    for (int off = 32; off >= 1; off >>= 1) v += __shfl_down(v, off);
    if (lane == 0) red_a[wave] = v;
    __syncthreads();
    if (wave == 0) {
        float vv = (lane < nw) ? red_a[lane] : 0.0f;
        for (int off = 32; off >= 1; off >>= 1) vv += __shfl_down(vv, off);
        if (lane == 0) s_std = sqrtf(vv / (s_cnt - 1.0f));
    }
    __syncthreads();

    if (tid < B && pos) {
        float ms    = (sn - mean) / (s_std + EPSF);
        float g_ang = -MARGIN * ms;           // added to theta at target col
        float g_add = MARGIN + MARGIN * ms;   // subtracted from cos at target col
        long idx = (long)tid * C + lab;
        float x = logits[idx];
        float theta = acosf(x) + g_ang;
        theta = fminf(fmaxf(theta, EPSF), (float)M_PI - EPSF);
        out[idx] = (cosf(theta) - g_add) * SCALE;
    }
}

extern "C" void kernel_launch(void* const* d_in, const int* in_sizes, int n_in,
                              void* d_out, int out_size, void* d_ws, size_t ws_size,
                              hipStream_t stream) {
    const float* logits = (const float*)d_in[0];
    const float* norms  = (const float*)d_in[1];
    const int*   labels = (const int*)d_in[2];
    float* out = (float*)d_out;

    int B = in_sizes[2];              // 1024
    long n = (long)in_sizes[0];       // B*C = 102,400,000
    int C = (int)(n / B);             // 100,000

    long n4 = n / 4;
    long tail_start = n4 * 4;

    int block = 256;
    int grid = 2048;                  // 256 CU * 8 blocks, grid-stride covers the rest

    adaface_scale_kernel<<<grid, block, 0, stream>>>(
        (const float4*)logits, (float4*)out, n4,
        logits, out, tail_start, n);

    adaface_fixup_kernel<<<1, 1024, 0, stream>>>(logits, norms, labels, out, B, C);
}

// Round 3
// 147.933 us; speedup vs baseline: 1.1843x; 1.1843x over previous
//
#include <hip/hip_runtime.h>
#include <math.h>

#define MARGIN 0.4f
#define EPSF   1e-3f
#define SCALE  64.0f
#define ELEMS_PER_THREAD 16   // float4s per thread in the bulk kernel

typedef float vfloat4 __attribute__((ext_vector_type(4)));  // clang-native, nontemporal-OK

// Bulk: out = logits * 64, vectorized float4, 16 float4/thread, nontemporal.
__global__ __launch_bounds__(256)
void adaface_scale_kernel(const vfloat4* __restrict__ in,
                          vfloat4* __restrict__ out,
                          long n4, const float* __restrict__ in_s,
                          float* __restrict__ out_s, long n_tail_start, long n) {
    long nthreads = (long)gridDim.x * blockDim.x;
    long i = (long)blockIdx.x * blockDim.x + threadIdx.x;

#pragma unroll
    for (int j = 0; j < ELEMS_PER_THREAD; ++j) {
        long k = i + (long)j * nthreads;
        if (k < n4) {
            vfloat4 v = __builtin_nontemporal_load(&in[k]);
            v *= SCALE;
            __builtin_nontemporal_store(v, &out[k]);
        }
    }
    // scalar tail (empty here: n % 4 == 0)
    for (long k = n_tail_start + i; k < n; k += nthreads) {
        out_s[k] = in_s[k] * SCALE;
    }
}

// Fixup: one block. Compute mean/std of clipped norms over positive rows,
// then rewrite the single target element of each positive row.
__global__ __launch_bounds__(1024)
void adaface_fixup_kernel(const float* __restrict__ logits,
                          const float* __restrict__ norms,
                          const int* __restrict__ labels,
                          float* __restrict__ out, int B, int C) {
    __shared__ float red_a[16];
    __shared__ float red_b[16];
    __shared__ float s_cnt, s_mean, s_std;

    int tid  = threadIdx.x;
    int lane = tid & 63;
    int wave = tid >> 6;
    int nw   = (blockDim.x + 63) >> 6;

    float sn  = 0.0f;
    int   lab = -1;
    bool  pos = false;
    if (tid < B) {
        sn  = fminf(fmaxf(norms[tid], 1e-3f), 100.0f);
        lab = labels[tid];
        pos = (lab != -1);
    }

    // Reduction 1: count of positives and sum of sn over positives.
    float a = pos ? 1.0f : 0.0f;
    float b = pos ? sn : 0.0f;
    for (int off = 32; off >= 1; off >>= 1) {
        a += __shfl_down(a, off);
        b += __shfl_down(b, off);
    }
    if (lane == 0) { red_a[wave] = a; red_b[wave] = b; }
    __syncthreads();
    if (wave == 0) {
        float aa = (lane < nw) ? red_a[lane] : 0.0f;
        float bb = (lane < nw) ? red_b[lane] : 0.0f;
        for (int off = 32; off >= 1; off >>= 1) {
            aa += __shfl_down(aa, off);
            bb += __shfl_down(bb, off);
        }
        if (lane == 0) { s_cnt = aa; s_mean = bb / aa; }
    }
    __syncthreads();

    // Reduction 2: unbiased variance over positives.
    float mean = s_mean;
    float d = sn - mean;
    float v = pos ? d * d : 0.0f;
    for (int off = 32; off >= 1; off >>= 1) v += __shfl_down(v, off);
    if (lane == 0) red_a[wave] = v;
    __syncthreads();
    if (wave == 0) {
        float vv = (lane < nw) ? red_a[lane] : 0.0f;
        for (int off = 32; off >= 1; off >>= 1) vv += __shfl_down(vv, off);
        if (lane == 0) s_std = sqrtf(vv / (s_cnt - 1.0f));
    }
    __syncthreads();

    if (tid < B && pos) {
        float ms    = (sn - mean) / (s_std + EPSF);
        float g_ang = -MARGIN * ms;           // added to theta at target col
        float g_add = MARGIN + MARGIN * ms;   // subtracted from cos at target col
        long idx = (long)tid * C + lab;
        float x = logits[idx];
        float theta = acosf(x) + g_ang;
        theta = fminf(fmaxf(theta, EPSF), (float)M_PI - EPSF);
        out[idx] = (cosf(theta) - g_add) * SCALE;
    }
}

extern "C" void kernel_launch(void* const* d_in, const int* in_sizes, int n_in,
                              void* d_out, int out_size, void* d_ws, size_t ws_size,
                              hipStream_t stream) {
    const float* logits = (const float*)d_in[0];
    const float* norms  = (const float*)d_in[1];
    const int*   labels = (const int*)d_in[2];
    float* out = (float*)d_out;

    int B = in_sizes[2];              // 1024
    long n = (long)in_sizes[0];       // B*C = 102,400,000
    int C = (int)(n / B);             // 100,000

    long n4 = n / 4;
    long tail_start = n4 * 4;

    int block = 256;
    long grid_l = (n4 + (long)block * ELEMS_PER_THREAD - 1) / ((long)block * ELEMS_PER_THREAD);
    int grid = (int)grid_l;           // 6250 for n4 = 25.6e6

    adaface_scale_kernel<<<grid, block, 0, stream>>>(
        (const vfloat4*)logits, (vfloat4*)out, n4,
        logits, out, tail_start, n);

    adaface_fixup_kernel<<<1, 1024, 0, stream>>>(logits, norms, labels, out, B, C);
}